// Round 8
// baseline (118.263 us; speedup 1.0000x reference)
//
#include <hip/hip_runtime.h>
#include <hip/hip_bf16.h>
#include <math.h>

#define DIN 512
#define DF 256
#define LSEQ 1024
#define NTOT 8192

typedef __attribute__((ext_vector_type(8))) short short8;
typedef __attribute__((ext_vector_type(4))) short short4v;
typedef __attribute__((ext_vector_type(4))) float f32x4;

__device__ __forceinline__ short f2bf(float x) {
  union { float f; unsigned u; } un; un.f = x;
  unsigned r = un.u + 0x7fffu + ((un.u >> 16) & 1u);  // RNE (inputs finite)
  return (short)(r >> 16);
}
__device__ __forceinline__ float bf2f(short s) {
  union { unsigned u; float f; } un; un.u = ((unsigned)(unsigned short)s) << 16;
  return un.f;
}

typedef __attribute__((address_space(1))) const unsigned char AS1c;
typedef __attribute__((address_space(3))) unsigned char AS3;
__device__ __forceinline__ void gload16(const void* g, void* l) {
  __builtin_amdgcn_global_load_lds((AS1c*)g, (AS3*)l, 16, 0, 0);
}
#define CFENCE() asm volatile("" ::: "memory")
#define L2E 1.44269504089f
#define THRL 11.5416f   // 8 nats in log2
#define LN2 0.69314718056f

// ---------- kernel 1: W [DIN][DF] f32 -> Wt [DF][DIN] bf16 (LDS transpose) ----
__global__ __launch_bounds__(256) void prep_w_kernel(const float* __restrict__ W,
                                                     short* __restrict__ Wt) {
  __shared__ short t[64 * 70];
  const int tid = threadIdx.x;
  const int k0 = (blockIdx.x & 7) * 64;    // 8 k-tiles
  const int c0 = (blockIdx.x >> 3) * 64;   // 4 c-tiles
  const int cl = tid & 63, kq = tid >> 6;  // read: c fast (coalesced)
#pragma unroll
  for (int r = 0; r < 16; ++r) {
    int kl = kq * 16 + r;
    t[cl * 70 + kl] = f2bf(W[(size_t)(k0 + kl) * DF + c0 + cl]);
  }
  __syncthreads();
  const int kl2 = tid & 63, cq = tid >> 6; // write: k fast (coalesced)
#pragma unroll
  for (int r = 0; r < 16; ++r) {
    int cl2 = cq * 16 + r;
    Wt[(size_t)(c0 + cl2) * DIN + k0 + kl2] = t[cl2 * 70 + kl2];
  }
}

// ---------- kernel 2: projection emb = relu(feat @ W + b), bf16 out ----------
#define PBM 64
#define PBK 64
#define PROW 72   // padded LDS row in shorts: 144B stride -> 2-lane/bank (free)

__global__ __launch_bounds__(256) void proj_kernel(const float* __restrict__ f1,
                                                   const float* __restrict__ f2,
                                                   const short* __restrict__ Wt,
                                                   const float* __restrict__ bias,
                                                   short* __restrict__ emb1,
                                                   short* __restrict__ emb2) {
  const float* feat = blockIdx.y ? f2 : f1;
  short* emb = blockIdx.y ? emb2 : emb1;
  __shared__ short ldsA[PBM * PROW];
  __shared__ short ldsB[DF * PROW];
  const int tid = threadIdx.x;
  const int lane = tid & 63, wv = tid >> 6;
  const int wrow = (wv & 1) * 32, wcol = (wv >> 1) * 128;
  const int l15 = lane & 15, lk = (lane >> 4) * 8;
  const int rowbase = blockIdx.x * PBM;

  f32x4 acc[2][8];
#pragma unroll
  for (int mi = 0; mi < 2; ++mi)
#pragma unroll
    for (int nf = 0; nf < 8; ++nf) acc[mi][nf] = f32x4{0.f, 0.f, 0.f, 0.f};

  for (int kb = 0; kb < DIN; kb += PBK) {
    __syncthreads();
#pragma unroll
    for (int i = 0; i < 4; ++i) {
      int flat = tid * 4 + i;
      int r = flat >> 4, kq = (flat & 15) * 4;
      f32x4 v = *(const f32x4*)(feat + (size_t)(rowbase + r) * DIN + kb + kq);
      short4v h;
      h[0] = f2bf(v[0]); h[1] = f2bf(v[1]); h[2] = f2bf(v[2]); h[3] = f2bf(v[3]);
      *(short4v*)(ldsA + r * PROW + kq) = h;
    }
#pragma unroll
    for (int i = 0; i < 8; ++i) {
      int c = tid, kq = i * 8;
      short8 v = *(const short8*)(Wt + (size_t)c * DIN + kb + kq);
      *(short8*)(ldsB + c * PROW + kq) = v;
    }
    __syncthreads();
#pragma unroll
    for (int kk = 0; kk < 2; ++kk) {
      short8 af[2], bf[8];
#pragma unroll
      for (int mi = 0; mi < 2; ++mi)
        af[mi] = *(const short8*)(ldsA + (wrow + mi * 16 + l15) * PROW + kk * 32 + lk);
#pragma unroll
      for (int nf = 0; nf < 8; ++nf)
        bf[nf] = *(const short8*)(ldsB + (wcol + nf * 16 + l15) * PROW + kk * 32 + lk);
#pragma unroll
      for (int mi = 0; mi < 2; ++mi)
#pragma unroll
        for (int nf = 0; nf < 8; ++nf)
          acc[mi][nf] = __builtin_amdgcn_mfma_f32_16x16x32_bf16(af[mi], bf[nf], acc[mi][nf], 0, 0, 0);
    }
  }
  const int r4 = (lane >> 4) * 4;
#pragma unroll
  for (int mi = 0; mi < 2; ++mi) {
    int row0 = rowbase + wrow + mi * 16 + r4;
#pragma unroll
    for (int nf = 0; nf < 8; ++nf) {
      int col = wcol + nf * 16 + l15;
      float bb = bias[col];
#pragma unroll
      for (int r = 0; r < 4; ++r) {
        float v = acc[mi][nf][r] + bb;
        v = v > 0.f ? v : 0.f;
        emb[(size_t)(row0 + r) * DF + col] = f2bf(v);
      }
    }
  }
}

// ---------- kernel 3: positive = dot(e1,e2) + banded diag means (LDS halo) ----
// 32 rows/block + 4-row halo each side staged in LDS (40 rows x 256 x 2 arrays
// = 40KB). 4 waves x 8 rows; 64 lanes per row; identical math to the
// refchecked global version, loads swapped to LDS (15x traffic cut).
#define POSR 32
#define PSTR 258   // row stride in shorts (4B pad)

__global__ __launch_bounds__(256) void positive_kernel(const short* __restrict__ emb1,
                                                       const short* __restrict__ emb2,
                                                       const int* __restrict__ prs,
                                                       const int* __restrict__ prt,
                                                       float* __restrict__ pos) {
  __shared__ short s1[40 * PSTR];
  __shared__ short s2[40 * PSTR];
  const int tid = threadIdx.x;
  const int b = blockIdx.x >> 5;          // 32 blocks per batch
  const int j0 = (blockIdx.x & 31) * POSR;
  const int rs = prs[0], rt = prt[0];

  // stage rows [j0-4, j0+36) clipped; 4 rows per iter, 64 lanes x short4 per row
  {
    const int rr = tid >> 6, c4 = (tid & 63) * 4;
#pragma unroll
    for (int it = 0; it < 10; ++it) {
      int r = it * 4 + rr;
      int g = j0 - 4 + r;
      short4v v1 = short4v{0, 0, 0, 0}, v2 = short4v{0, 0, 0, 0};
      if (g >= 0 && g < LSEQ) {
        size_t off = (size_t)(b * LSEQ + g) * DF + c4;
        v1 = *(const short4v*)(emb1 + off);
        v2 = *(const short4v*)(emb2 + off);
      }
      *(short4v*)(s1 + r * PSTR + c4) = v1;
      *(short4v*)(s2 + r * PSTR + c4) = v2;
    }
  }
  __syncthreads();

  const int lane = tid & 63, wv = tid >> 6;
  for (int q = 0; q < 8; ++q) {
    const int j = j0 + wv * 8 + q;
    const int rl = wv * 8 + q + 4;
    float a1[4], a2[4];
    {
      short4v v1 = *(const short4v*)(s1 + rl * PSTR + lane * 4);
      short4v v2 = *(const short4v*)(s2 + rl * PSTR + lane * 4);
#pragma unroll
      for (int i = 0; i < 4; ++i) { a1[i] = bf2f(v1[i]); a2[i] = bf2f(v2[i]); }
    }
    float dot12 = 0.f, p11 = 0.f, p22 = 0.f, p12 = 0.f;
#pragma unroll
    for (int i = 0; i < 4; ++i) dot12 += a1[i] * a2[i];
    int rmax = rs > rt ? rs : rt;
    for (int d = -rmax; d <= rmax; ++d) {
      int k = j + d;
      if (k < 0 || k >= LSEQ) continue;
      int kl = rl + d;
      short4v w1 = *(const short4v*)(s1 + kl * PSTR + lane * 4);
      short4v w2 = *(const short4v*)(s2 + kl * PSTR + lane * 4);
      float d11 = 0.f, d22 = 0.f, d12 = 0.f;
#pragma unroll
      for (int i = 0; i < 4; ++i) {
        float e1k = bf2f(w1[i]), e2k = bf2f(w2[i]);
        d11 += a1[i] * e1k;
        d22 += a2[i] * e2k;
        d12 += a1[i] * e2k;
      }
      if (d >= -rs && d <= rs) { p11 += d11; p22 += d22; }
      if (d >= -rt && d <= rt) { p12 += d12; }
    }
#pragma unroll
    for (int m = 1; m < 64; m <<= 1) {
      dot12 += __shfl_xor(dot12, m);
      p11 += __shfl_xor(p11, m);
      p22 += __shfl_xor(p22, m);
      p12 += __shfl_xor(p12, m);
    }
    if (lane == 0) {
      float res = dot12;
      if (rs > 0) {
        int lo = j - rs < 0 ? 0 : j - rs;
        int hi = j + rs > LSEQ - 1 ? LSEQ - 1 : j + rs;
        res += (p11 + p22) / (float)(hi - lo + 1);
      }
      if (rt > 0) {
        int lo = j - rt < 0 ? 0 : j - rt;
        int hi = j + rt > LSEQ - 1 ? LSEQ - 1 : j + rt;
        res += p12 / (float)(hi - lo + 1);
      }
      pos[b * LSEQ + j] = res;
    }
  }
}

// ---------- kernel 4: flash-style row logsumexp of e1 @ e2^T ----------
// R4 skeleton (proven: gload_lds, [kblk][col] layout, 0 conflicts, counted
// vmcnt(4)) + TRIPLE buffer (3x16KB) -> ONE barrier per tile. Race-free:
// every ds_read is consumed by an MFMA before the barrier, so all reads of
// tile t-1 completed before any wave passes barrier(t); stage(t+2) targets
// the buffer whose last readers were tile t-1. Log2-domain wave-uniform
// defer-max softmax (R6/R7-proven math).
#define NBM 128
#define NBN 32
#define NCHUNK 16
#define CHW (NTOT / NCHUNK)   // 512
#define NT (CHW / NBN)        // 16

__global__ __launch_bounds__(256, 3) void negative_kernel(const short* __restrict__ e1,
                                                          const short* __restrict__ e2,
                                                          float* __restrict__ mpart,
                                                          float* __restrict__ spart) {
  __shared__ short ldsB[3][NBN * DF];   // 3 x 16KB
  const int tid = threadIdx.x;
  const int lane = tid & 63, wv = tid >> 6;
  const int l15 = lane & 15, lk16 = lane >> 4;
  const int rowbase = blockIdx.x * NBM + wv * 32;
  const short* colbase = e2 + (size_t)(blockIdx.y * CHW) * DF;

  // granule G = i*256 + tid -> col = tid&31, k8 = i*8 + (tid>>5)
  const int src_off = (tid & 31) * DF + (tid >> 5) * 8;
  const int dst_off = wv * 512;   // shorts; + i*2048

  auto stage = [&](int tt) {
    const short* nb = colbase + (size_t)tt * NBN * DF + src_off;
    short* db = (short*)ldsB[tt % 3] + dst_off;
#pragma unroll
    for (int i = 0; i < 4; ++i)
      gload16(nb + i * 64, db + i * 2048);
  };

  stage(0);
  CFENCE();
  // A fragments between stage(0) and stage(1): vmcnt(4) at t=0 drains them
  short8 a[2][8];
#pragma unroll
  for (int mi = 0; mi < 2; ++mi)
#pragma unroll
    for (int ks = 0; ks < 8; ++ks)
      a[mi][ks] = *(const short8*)(e1 + (size_t)(rowbase + mi * 16 + l15) * DF + ks * 32 + lk16 * 8);
  CFENCE();
  stage(1);
  CFENCE();

  float mrunL[8], srun[8];
#pragma unroll
  for (int i = 0; i < 8; ++i) { mrunL[i] = 0.f; srun[i] = 0.f; }

  for (int t = 0; t < NT; ++t) {
    if (t < NT - 1) asm volatile("s_waitcnt vmcnt(4)" ::: "memory");
    else            asm volatile("s_waitcnt vmcnt(0)" ::: "memory");
    __builtin_amdgcn_s_barrier();      // buf[t%3] fully staged for all waves
    const short* bbase = (const short*)ldsB[t % 3] + lk16 * 256 + l15 * 8;

    f32x4 acc[2][2];
#pragma unroll
    for (int mi = 0; mi < 2; ++mi)
#pragma unroll
      for (int nf = 0; nf < 2; ++nf) acc[mi][nf] = f32x4{0.f, 0.f, 0.f, 0.f};

    __builtin_amdgcn_s_setprio(1);
#pragma unroll
    for (int ks = 0; ks < 8; ++ks) {
      short8 b0 = *(const short8*)(bbase + ks * 1024);
      short8 b1 = *(const short8*)(bbase + ks * 1024 + 128);
#pragma unroll
      for (int mi = 0; mi < 2; ++mi) {
        acc[mi][0] = __builtin_amdgcn_mfma_f32_16x16x32_bf16(a[mi][ks], b0, acc[mi][0], 0, 0, 0);
        acc[mi][1] = __builtin_amdgcn_mfma_f32_16x16x32_bf16(a[mi][ks], b1, acc[mi][1], 0, 0, 0);
      }
    }
    __builtin_amdgcn_s_setprio(0);
    CFENCE();
    if (t + 2 < NT) stage(t + 2);      // buffer last read at t-1; all waves past barrier(t)

    // log2-domain online softmax, wave-uniform defer (THR = 8 nats)
    float e0[8], e1v[8];
    bool nd = false;
#pragma unroll
    for (int s = 0; s < 8; ++s) {
      float v0 = acc[s >> 2][0][s & 3], v1 = acc[s >> 2][1][s & 3];
      e0[s] = __builtin_fmaf(v0, L2E, -mrunL[s]);
      e1v[s] = __builtin_fmaf(v1, L2E, -mrunL[s]);
      nd = nd || (e0[s] > THRL) || (e1v[s] > THRL);
    }
    if (__any(nd)) {
#pragma unroll
      for (int s = 0; s < 8; ++s) {
        float mxL = fmaxf(e0[s], e1v[s]) + mrunL[s];
        float mnL = fmaxf(mrunL[s], mxL);
        srun[s] = srun[s] * exp2f(mrunL[s] - mnL)
                + exp2f(e0[s] + mrunL[s] - mnL)
                + exp2f(e1v[s] + mrunL[s] - mnL);
        mrunL[s] = mnL;
      }
    } else {
#pragma unroll
      for (int s = 0; s < 8; ++s)
        srun[s] += exp2f(e0[s]) + exp2f(e1v[s]);
    }
  }

  // merge (mL,s) across the 16 lanes (cols) of each row, write log2-domain partials
#pragma unroll
  for (int s = 0; s < 8; ++s) {
    float m = mrunL[s], sv = srun[s];
#pragma unroll
    for (int msk = 1; msk < 16; msk <<= 1) {
      float mo = __shfl_xor(m, msk);
      float so = __shfl_xor(sv, msk);
      float mn = fmaxf(m, mo);
      sv = sv * exp2f(m - mn) + so * exp2f(mo - mn);
      m = mn;
    }
    if (l15 == 0) {
      int row = rowbase + (s >> 2) * 16 + lk16 * 4 + (s & 3);
      mpart[blockIdx.y * NTOT + row] = m;
      spart[blockIdx.y * NTOT + row] = sv;
    }
  }
}

// ---------- kernel 5a: per-row lse - pos (partials in log2 domain) ----------
__global__ __launch_bounds__(256) void finalize1_kernel(const float* __restrict__ pos,
                                                        const float* __restrict__ mpart,
                                                        const float* __restrict__ spart,
                                                        float* __restrict__ partial) {
  __shared__ float red[4];
  int row = blockIdx.x * 256 + threadIdx.x;
  float m = -1e30f;
#pragma unroll
  for (int c = 0; c < NCHUNK; ++c) m = fmaxf(m, mpart[c * NTOT + row]);
  float s = 0.f;
#pragma unroll
  for (int c = 0; c < NCHUNK; ++c) s += spart[c * NTOT + row] * exp2f(mpart[c * NTOT + row] - m);
  float v = (m + log2f(s)) * LN2 - pos[row];
#pragma unroll
  for (int msk = 1; msk < 64; msk <<= 1) v += __shfl_xor(v, msk);
  if ((threadIdx.x & 63) == 0) red[threadIdx.x >> 6] = v;
  __syncthreads();
  if (threadIdx.x == 0) partial[blockIdx.x] = red[0] + red[1] + red[2] + red[3];
}

// ---------- kernel 5b: final scalar ----------
__global__ __launch_bounds__(64) void finalize2_kernel(const float* __restrict__ partial,
                                                       float* __restrict__ out) {
  int lane = threadIdx.x;
  float v = lane < 32 ? partial[lane] : 0.f;
#pragma unroll
  for (int msk = 1; msk < 64; msk <<= 1) v += __shfl_xor(v, msk);
  if (lane == 0) out[0] = v / (float)NTOT - logf((float)NTOT);
}

extern "C" void kernel_launch(void* const* d_in, const int* in_sizes, int n_in,
                              void* d_out, int out_size, void* d_ws, size_t ws_size,
                              hipStream_t stream) {
  const float* f1 = (const float*)d_in[0];
  const float* f2 = (const float*)d_in[1];
  const float* W = (const float*)d_in[2];
  const float* bias = (const float*)d_in[3];
  const int* prs = (const int*)d_in[4];
  const int* prt = (const int*)d_in[5];
  float* out = (float*)d_out;

  char* ws = (char*)d_ws;
  short* Wt = (short*)(ws);                                  // 256 KB @ 0
  short* emb1 = (short*)(ws + 262144);                       // 4 MB
  short* emb2 = (short*)(ws + 262144 + 4194304);             // 4 MB
  float* pos = (float*)(ws + 8650752);                       // 32 KB
  float* mpart = (float*)(ws + 8683520);                     // 512 KB
  float* spart = (float*)(ws + 9207808);                     // 512 KB
  float* partial = (float*)(ws + 9732096);                   // 128 B

  prep_w_kernel<<<32, 256, 0, stream>>>(W, Wt);
  proj_kernel<<<dim3(NTOT / PBM, 2), 256, 0, stream>>>(f1, f2, Wt, bias, emb1, emb2);
  positive_kernel<<<NTOT / POSR, 256, 0, stream>>>(emb1, emb2, prs, prt, pos);
  negative_kernel<<<dim3(NTOT / NBM, NCHUNK), 256, 0, stream>>>(emb1, emb2, mpart, spart);
  finalize1_kernel<<<32, 256, 0, stream>>>(pos, mpart, spart, partial);
  finalize2_kernel<<<1, 64, 0, stream>>>(partial, out);
}

// Round 9
// 96.601 us; speedup vs baseline: 1.2242x; 1.2242x over previous
//
#include <hip/hip_runtime.h>
#include <hip/hip_bf16.h>
#include <math.h>

#define DIN 512
#define DF 256
#define LSEQ 1024
#define NTOT 8192

typedef __attribute__((ext_vector_type(8))) short short8;
typedef __attribute__((ext_vector_type(4))) short short4v;
typedef __attribute__((ext_vector_type(4))) float f32x4;

__device__ __forceinline__ short f2bf(float x) {
  union { float f; unsigned u; } un; un.f = x;
  unsigned r = un.u + 0x7fffu + ((un.u >> 16) & 1u);  // RNE (inputs finite)
  return (short)(r >> 16);
}
__device__ __forceinline__ float bf2f(short s) {
  union { unsigned u; float f; } un; un.u = ((unsigned)(unsigned short)s) << 16;
  return un.f;
}

typedef __attribute__((address_space(1))) const unsigned char AS1c;
typedef __attribute__((address_space(3))) unsigned char AS3;
__device__ __forceinline__ void gload16(const void* g, void* l) {
  __builtin_amdgcn_global_load_lds((AS1c*)g, (AS3*)l, 16, 0, 0);
}
#define CFENCE() asm volatile("" ::: "memory")
#define EXP2R(x) __builtin_amdgcn_exp2f(x)   // raw v_exp_f32 (exp2f libcall ~10 insts)
#define L2E 1.44269504089f
#define THRL 11.5416f   // 8 nats in log2
#define LN2 0.69314718056f

// ---------- kernel 1: W [DIN][DF] f32 -> Wt [DF][DIN] bf16 (LDS transpose) ----
__global__ __launch_bounds__(256) void prep_w_kernel(const float* __restrict__ W,
                                                     short* __restrict__ Wt) {
  __shared__ short t[64 * 70];
  const int tid = threadIdx.x;
  const int k0 = (blockIdx.x & 7) * 64;    // 8 k-tiles
  const int c0 = (blockIdx.x >> 3) * 64;   // 4 c-tiles
  const int cl = tid & 63, kq = tid >> 6;  // read: c fast (coalesced)
#pragma unroll
  for (int r = 0; r < 16; ++r) {
    int kl = kq * 16 + r;
    t[cl * 70 + kl] = f2bf(W[(size_t)(k0 + kl) * DF + c0 + cl]);
  }
  __syncthreads();
  const int kl2 = tid & 63, cq = tid >> 6; // write: k fast (coalesced)
#pragma unroll
  for (int r = 0; r < 16; ++r) {
    int cl2 = cq * 16 + r;
    Wt[(size_t)(c0 + cl2) * DIN + k0 + kl2] = t[cl2 * 70 + kl2];
  }
}

// ---------- kernel 2: projection emb = relu(feat @ W + b), bf16 out ----------
#define PBM 64
#define PBK 64
#define PROW 72   // padded LDS row in shorts: 144B stride -> 2-lane/bank (free)

__global__ __launch_bounds__(256) void proj_kernel(const float* __restrict__ f1,
                                                   const float* __restrict__ f2,
                                                   const short* __restrict__ Wt,
                                                   const float* __restrict__ bias,
                                                   short* __restrict__ emb1,
                                                   short* __restrict__ emb2) {
  const float* feat = blockIdx.y ? f2 : f1;
  short* emb = blockIdx.y ? emb2 : emb1;
  __shared__ short ldsA[PBM * PROW];
  __shared__ short ldsB[DF * PROW];
  const int tid = threadIdx.x;
  const int lane = tid & 63, wv = tid >> 6;
  const int wrow = (wv & 1) * 32, wcol = (wv >> 1) * 128;
  const int l15 = lane & 15, lk = (lane >> 4) * 8;
  const int rowbase = blockIdx.x * PBM;

  f32x4 acc[2][8];
#pragma unroll
  for (int mi = 0; mi < 2; ++mi)
#pragma unroll
    for (int nf = 0; nf < 8; ++nf) acc[mi][nf] = f32x4{0.f, 0.f, 0.f, 0.f};

  for (int kb = 0; kb < DIN; kb += PBK) {
    __syncthreads();
#pragma unroll
    for (int i = 0; i < 4; ++i) {
      int flat = tid * 4 + i;
      int r = flat >> 4, kq = (flat & 15) * 4;
      f32x4 v = *(const f32x4*)(feat + (size_t)(rowbase + r) * DIN + kb + kq);
      short4v h;
      h[0] = f2bf(v[0]); h[1] = f2bf(v[1]); h[2] = f2bf(v[2]); h[3] = f2bf(v[3]);
      *(short4v*)(ldsA + r * PROW + kq) = h;
    }
#pragma unroll
    for (int i = 0; i < 8; ++i) {
      int c = tid, kq = i * 8;
      short8 v = *(const short8*)(Wt + (size_t)c * DIN + kb + kq);
      *(short8*)(ldsB + c * PROW + kq) = v;
    }
    __syncthreads();
#pragma unroll
    for (int kk = 0; kk < 2; ++kk) {
      short8 af[2], bf[8];
#pragma unroll
      for (int mi = 0; mi < 2; ++mi)
        af[mi] = *(const short8*)(ldsA + (wrow + mi * 16 + l15) * PROW + kk * 32 + lk);
#pragma unroll
      for (int nf = 0; nf < 8; ++nf)
        bf[nf] = *(const short8*)(ldsB + (wcol + nf * 16 + l15) * PROW + kk * 32 + lk);
#pragma unroll
      for (int mi = 0; mi < 2; ++mi)
#pragma unroll
        for (int nf = 0; nf < 8; ++nf)
          acc[mi][nf] = __builtin_amdgcn_mfma_f32_16x16x32_bf16(af[mi], bf[nf], acc[mi][nf], 0, 0, 0);
    }
  }
  const int r4 = (lane >> 4) * 4;
#pragma unroll
  for (int mi = 0; mi < 2; ++mi) {
    int row0 = rowbase + wrow + mi * 16 + r4;
#pragma unroll
    for (int nf = 0; nf < 8; ++nf) {
      int col = wcol + nf * 16 + l15;
      float bb = bias[col];
#pragma unroll
      for (int r = 0; r < 4; ++r) {
        float v = acc[mi][nf][r] + bb;
        v = v > 0.f ? v : 0.f;
        emb[(size_t)(row0 + r) * DF + col] = f2bf(v);
      }
    }
  }
}

// ---------- kernel 3: positive = dot(e1,e2) + banded diag means (LDS halo) ----
#define POSR 32
#define PSTR 258   // row stride in shorts (4B pad)

__global__ __launch_bounds__(256) void positive_kernel(const short* __restrict__ emb1,
                                                       const short* __restrict__ emb2,
                                                       const int* __restrict__ prs,
                                                       const int* __restrict__ prt,
                                                       float* __restrict__ pos) {
  __shared__ short s1[40 * PSTR];
  __shared__ short s2[40 * PSTR];
  const int tid = threadIdx.x;
  const int b = blockIdx.x >> 5;          // 32 blocks per batch
  const int j0 = (blockIdx.x & 31) * POSR;
  const int rs = prs[0], rt = prt[0];

  {
    const int rr = tid >> 6, c4 = (tid & 63) * 4;
#pragma unroll
    for (int it = 0; it < 10; ++it) {
      int r = it * 4 + rr;
      int g = j0 - 4 + r;
      short4v v1 = short4v{0, 0, 0, 0}, v2 = short4v{0, 0, 0, 0};
      if (g >= 0 && g < LSEQ) {
        size_t off = (size_t)(b * LSEQ + g) * DF + c4;
        v1 = *(const short4v*)(emb1 + off);
        v2 = *(const short4v*)(emb2 + off);
      }
      *(short4v*)(s1 + r * PSTR + c4) = v1;
      *(short4v*)(s2 + r * PSTR + c4) = v2;
    }
  }
  __syncthreads();

  const int lane = tid & 63, wv = tid >> 6;
  for (int q = 0; q < 8; ++q) {
    const int j = j0 + wv * 8 + q;
    const int rl = wv * 8 + q + 4;
    float a1[4], a2[4];
    {
      short4v v1 = *(const short4v*)(s1 + rl * PSTR + lane * 4);
      short4v v2 = *(const short4v*)(s2 + rl * PSTR + lane * 4);
#pragma unroll
      for (int i = 0; i < 4; ++i) { a1[i] = bf2f(v1[i]); a2[i] = bf2f(v2[i]); }
    }
    float dot12 = 0.f, p11 = 0.f, p22 = 0.f, p12 = 0.f;
#pragma unroll
    for (int i = 0; i < 4; ++i) dot12 += a1[i] * a2[i];
    int rmax = rs > rt ? rs : rt;
    for (int d = -rmax; d <= rmax; ++d) {
      int k = j + d;
      if (k < 0 || k >= LSEQ) continue;
      int kl = rl + d;
      short4v w1 = *(const short4v*)(s1 + kl * PSTR + lane * 4);
      short4v w2 = *(const short4v*)(s2 + kl * PSTR + lane * 4);
      float d11 = 0.f, d22 = 0.f, d12 = 0.f;
#pragma unroll
      for (int i = 0; i < 4; ++i) {
        float e1k = bf2f(w1[i]), e2k = bf2f(w2[i]);
        d11 += a1[i] * e1k;
        d22 += a2[i] * e2k;
        d12 += a1[i] * e2k;
      }
      if (d >= -rs && d <= rs) { p11 += d11; p22 += d22; }
      if (d >= -rt && d <= rt) { p12 += d12; }
    }
#pragma unroll
    for (int m = 1; m < 64; m <<= 1) {
      dot12 += __shfl_xor(dot12, m);
      p11 += __shfl_xor(p11, m);
      p22 += __shfl_xor(p22, m);
      p12 += __shfl_xor(p12, m);
    }
    if (lane == 0) {
      float res = dot12;
      if (rs > 0) {
        int lo = j - rs < 0 ? 0 : j - rs;
        int hi = j + rs > LSEQ - 1 ? LSEQ - 1 : j + rs;
        res += (p11 + p22) / (float)(hi - lo + 1);
      }
      if (rt > 0) {
        int lo = j - rt < 0 ? 0 : j - rt;
        int hi = j + rt > LSEQ - 1 ? LSEQ - 1 : j + rt;
        res += p12 / (float)(hi - lo + 1);
      }
      pos[b * LSEQ + j] = res;
    }
  }
}

// ---------- kernel 4: flash-style row logsumexp of e1 @ e2^T ----------
// R4 skeleton VERBATIM (best measured: gload_lds staging, [kblk][col] layout,
// 0 bank conflicts, double buffer 2x16KB, counted vmcnt(4), 2 raw barriers,
// 3 blocks/CU). Only change vs R4: softmax is log2-domain wave-uniform
// defer-max with RAW v_exp_f32 (builtin exp2) — R6-R8's regressions traced
// to exp2f/log2f OCML libcalls (~10 insts each), not to the schedule.
#define NBM 128
#define NBN 32
#define NCHUNK 16
#define CHW (NTOT / NCHUNK)   // 512
#define NT (CHW / NBN)        // 16

__global__ __launch_bounds__(256, 3) void negative_kernel(const short* __restrict__ e1,
                                                          const short* __restrict__ e2,
                                                          float* __restrict__ mpart,
                                                          float* __restrict__ spart) {
  __shared__ short ldsB[2][NBN * DF];   // 2 x 16KB, granule (kblk*32+col)
  const int tid = threadIdx.x;
  const int lane = tid & 63, wv = tid >> 6;
  const int l15 = lane & 15, lk16 = lane >> 4;
  const int rowbase = blockIdx.x * NBM + wv * 32;
  const short* colbase = e2 + (size_t)(blockIdx.y * CHW) * DF;

  const int src_off = (tid & 31) * DF + (tid >> 5) * 8;
  const int dst_off = wv * 512;

  auto stage = [&](int tt) {
    const short* nb = colbase + (size_t)tt * NBN * DF + src_off;
    short* db = (short*)ldsB[tt & 1] + dst_off;
#pragma unroll
    for (int i = 0; i < 4; ++i)
      gload16(nb + i * 64, db + i * 2048);
  };

  stage(0);
  CFENCE();
  short8 a[2][8];
#pragma unroll
  for (int mi = 0; mi < 2; ++mi)
#pragma unroll
    for (int ks = 0; ks < 8; ++ks)
      a[mi][ks] = *(const short8*)(e1 + (size_t)(rowbase + mi * 16 + l15) * DF + ks * 32 + lk16 * 8);
  CFENCE();
  stage(1);
  CFENCE();

  float mrunL[8], srun[8];
#pragma unroll
  for (int i = 0; i < 8; ++i) { mrunL[i] = 0.f; srun[i] = 0.f; }

  for (int t = 0; t < NT; ++t) {
    if (t < NT - 1) asm volatile("s_waitcnt vmcnt(4)" ::: "memory");
    else            asm volatile("s_waitcnt vmcnt(0)" ::: "memory");
    __builtin_amdgcn_s_barrier();      // buf[t&1] fully staged for all waves
    const short* bbase = (const short*)ldsB[t & 1] + lk16 * 256 + l15 * 8;

    f32x4 acc[2][2];
#pragma unroll
    for (int mi = 0; mi < 2; ++mi)
#pragma unroll
      for (int nf = 0; nf < 2; ++nf) acc[mi][nf] = f32x4{0.f, 0.f, 0.f, 0.f};

    __builtin_amdgcn_s_setprio(1);
#pragma unroll
    for (int ks = 0; ks < 8; ++ks) {
      short8 b0 = *(const short8*)(bbase + ks * 1024);
      short8 b1 = *(const short8*)(bbase + ks * 1024 + 128);
#pragma unroll
      for (int mi = 0; mi < 2; ++mi) {
        acc[mi][0] = __builtin_amdgcn_mfma_f32_16x16x32_bf16(a[mi][ks], b0, acc[mi][0], 0, 0, 0);
        acc[mi][1] = __builtin_amdgcn_mfma_f32_16x16x32_bf16(a[mi][ks], b1, acc[mi][1], 0, 0, 0);
      }
    }
    __builtin_amdgcn_s_setprio(0);

    // log2-domain online softmax, wave-uniform defer (THR = 8 nats), raw exp2
    float g0[8], g1[8], m01[8];
#pragma unroll
    for (int s = 0; s < 8; ++s) {
      float v0 = acc[s >> 2][0][s & 3], v1 = acc[s >> 2][1][s & 3];
      g0[s] = __builtin_fmaf(v0, L2E, -mrunL[s]);
      g1[s] = __builtin_fmaf(v1, L2E, -mrunL[s]);
      m01[s] = fmaxf(g0[s], g1[s]);
    }
    float x0 = fmaxf(fmaxf(m01[0], m01[1]), fmaxf(m01[2], m01[3]));
    float x1 = fmaxf(fmaxf(m01[4], m01[5]), fmaxf(m01[6], m01[7]));
    if (__builtin_expect(__any(fmaxf(x0, x1) > THRL), 0)) {
#pragma unroll
      for (int s = 0; s < 8; ++s) {
        float dL = fmaxf(m01[s], 0.f);   // mnL - mrunL in log2
        srun[s] = srun[s] * EXP2R(-dL) + EXP2R(g0[s] - dL) + EXP2R(g1[s] - dL);
        mrunL[s] += dL;
      }
    } else {
#pragma unroll
      for (int s = 0; s < 8; ++s)
        srun[s] += EXP2R(g0[s]) + EXP2R(g1[s]);
    }
    __builtin_amdgcn_s_barrier();      // all waves done reading buf[t&1]
    CFENCE();
    if (t + 2 < NT) stage(t + 2);      // refill just-consumed buffer; stays in flight
  }

  // merge (mL,s) across the 16 lanes (cols) of each row, write log2-domain partials
#pragma unroll
  for (int s = 0; s < 8; ++s) {
    float m = mrunL[s], sv = srun[s];
#pragma unroll
    for (int msk = 1; msk < 16; msk <<= 1) {
      float mo = __shfl_xor(m, msk);
      float so = __shfl_xor(sv, msk);
      float mn = fmaxf(m, mo);
      sv = sv * EXP2R(m - mn) + so * EXP2R(mo - mn);
      m = mn;
    }
    if (l15 == 0) {
      int row = rowbase + (s >> 2) * 16 + lk16 * 4 + (s & 3);
      mpart[blockIdx.y * NTOT + row] = m;
      spart[blockIdx.y * NTOT + row] = sv;
    }
  }
}

// ---------- kernel 5a: per-row lse - pos (partials in log2 domain) ----------
__global__ __launch_bounds__(256) void finalize1_kernel(const float* __restrict__ pos,
                                                        const float* __restrict__ mpart,
                                                        const float* __restrict__ spart,
                                                        float* __restrict__ partial) {
  __shared__ float red[4];
  int row = blockIdx.x * 256 + threadIdx.x;
  float m = -1e30f;
#pragma unroll
  for (int c = 0; c < NCHUNK; ++c) m = fmaxf(m, mpart[c * NTOT + row]);
  float s = 0.f;
#pragma unroll
  for (int c = 0; c < NCHUNK; ++c) s += spart[c * NTOT + row] * EXP2R(mpart[c * NTOT + row] - m);
  float v = (m + __builtin_amdgcn_logf(s)) * LN2 - pos[row];
#pragma unroll
  for (int msk = 1; msk < 64; msk <<= 1) v += __shfl_xor(v, msk);
  if ((threadIdx.x & 63) == 0) red[threadIdx.x >> 6] = v;
  __syncthreads();
  if (threadIdx.x == 0) partial[blockIdx.x] = red[0] + red[1] + red[2] + red[3];
}

// ---------- kernel 5b: final scalar ----------
__global__ __launch_bounds__(64) void finalize2_kernel(const float* __restrict__ partial,
                                                       float* __restrict__ out) {
  int lane = threadIdx.x;
  float v = lane < 32 ? partial[lane] : 0.f;
#pragma unroll
  for (int msk = 1; msk < 64; msk <<= 1) v += __shfl_xor(v, msk);
  if (lane == 0) out[0] = v / (float)NTOT - logf((float)NTOT);
}

extern "C" void kernel_launch(void* const* d_in, const int* in_sizes, int n_in,
                              void* d_out, int out_size, void* d_ws, size_t ws_size,
                              hipStream_t stream) {
  const float* f1 = (const float*)d_in[0];
  const float* f2 = (const float*)d_in[1];
  const float* W = (const float*)d_in[2];
  const float* bias = (const float*)d_in[3];
  const int* prs = (const int*)d_in[4];
  const int* prt = (const int*)d_in[5];
  float* out = (float*)d_out;

  char* ws = (char*)d_ws;
  short* Wt = (short*)(ws);                                  // 256 KB @ 0
  short* emb1 = (short*)(ws + 262144);                       // 4 MB
  short* emb2 = (short*)(ws + 262144 + 4194304);             // 4 MB
  float* pos = (float*)(ws + 8650752);                       // 32 KB
  float* mpart = (float*)(ws + 8683520);                     // 512 KB
  float* spart = (float*)(ws + 9207808);                     // 512 KB
  float* partial = (float*)(ws + 9732096);                   // 128 B

  prep_w_kernel<<<32, 256, 0, stream>>>(W, Wt);
  proj_kernel<<<dim3(NTOT / PBM, 2), 256, 0, stream>>>(f1, f2, Wt, bias, emb1, emb2);
  positive_kernel<<<NTOT / POSR, 256, 0, stream>>>(emb1, emb2, prs, prt, pos);
  negative_kernel<<<dim3(NTOT / NBM, NCHUNK), 256, 0, stream>>>(emb1, emb2, mpart, spart);
  finalize1_kernel<<<32, 256, 0, stream>>>(pos, mpart, spart, partial);
  finalize2_kernel<<<1, 64, 0, stream>>>(partial, out);
}